// Round 1
// baseline (948.511 us; speedup 1.0000x reference)
//
#include <hip/hip_runtime.h>
#include <hip/hip_bf16.h>
#include <stdint.h>

#define S_LEN 2048
#define NB 2
#define NH 16
#define HDIM 128
#define RDIM 64
#define DF 192          // HDIM + RDIM
#define MROWS 4096      // NB * S_LEN

typedef __bf16 bf16_t;
typedef __attribute__((ext_vector_type(8))) __bf16 bf16x8;
typedef __attribute__((ext_vector_type(4))) __bf16 bf16x4;
typedef __attribute__((ext_vector_type(4))) float f32x4;
typedef __attribute__((ext_vector_type(4))) float float4v;

__device__ __forceinline__ void gload_lds16(const bf16_t* g, bf16_t* l) {
  __builtin_amdgcn_global_load_lds(
      (const __attribute__((address_space(1))) void*)g,
      (__attribute__((address_space(3))) void*)l, 16, 0, 0);
}

// ---------------- convert f32 -> bf16 (contiguous) ----------------
__global__ __launch_bounds__(256) void convert_bf16(const float* __restrict__ in,
                                                    bf16_t* __restrict__ out, int n4) {
  int i = blockIdx.x * 256 + threadIdx.x;
  if (i >= n4) return;
  float4v v = *reinterpret_cast<const float4v*>(&in[(size_t)i * 4]);
  bf16x4 o;
  o[0] = (bf16_t)v[0]; o[1] = (bf16_t)v[1]; o[2] = (bf16_t)v[2]; o[3] = (bf16_t)v[3];
  *reinterpret_cast<bf16x4*>(&out[(size_t)i * 4]) = o;
}

// ---------------- transpose (K,N) f32 -> (N,K) bf16 ----------------
__global__ __launch_bounds__(256) void transpose_bf16(const float* __restrict__ in,
                                                      bf16_t* __restrict__ out,
                                                      int K, int N) {
  __shared__ float t[64][65];
  const int n0 = blockIdx.x * 64, k0 = blockIdx.y * 64;
  const int tx = threadIdx.x & 63, ty = threadIdx.x >> 6;
#pragma unroll
  for (int i = ty; i < 64; i += 4)
    t[i][tx] = in[(size_t)(k0 + i) * N + n0 + tx];
  __syncthreads();
#pragma unroll
  for (int i = ty; i < 64; i += 4)
    out[(size_t)(n0 + i) * K + k0 + tx] = (bf16_t)t[tx][i];
}

// ---------------- GEMM: C(M,N) = A(M,K) * Bt(N,K)^T, bf16 in, epilogue modes ----
// MODE 0: plain bf16 out[row*N+col]
// MODE 1: f32 out + bias  (final projection)
// MODE 2: scatter to qf/kf (B,H,S,192), d < 128  (col = h*128+d)
// MODE 3: scatter to vT (B,H,128,S)             (col = h*128+d)
// MODE 4: bias + RoPE + scatter to qf/kf offset 128 (col = h*64+dr)
struct EpiParams {
  bf16_t* out;
  float* outf;
  const float* bias;
  const float* cosb;
  const float* sinb;
};

template <int MODE>
__global__ __launch_bounds__(256) void gemm_bt(const bf16_t* __restrict__ A,
                                               const bf16_t* __restrict__ Bt,
                                               int M, int N, int K, EpiParams ep) {
  const int tid = threadIdx.x;
  const int lane = tid & 63, w = tid >> 6;
  const int l15 = lane & 15, lg = lane >> 4;
  const int m0 = blockIdx.y * 128, n0 = blockIdx.x * 128;
  const int mw = (w >> 1) * 64, nw = (w & 1) * 64;
  __shared__ alignas(16) bf16_t As[128 * 32];
  __shared__ alignas(16) bf16_t Bs[128 * 32];

  f32x4 acc[4][4] = {};
  const int row_ld = tid >> 2;            // 0..63
  const int col8 = (tid & 3) * 8;
  const bf16_t* ag = A + (size_t)(m0 + row_ld) * K + col8;
  const bf16_t* bg = Bt + (size_t)(n0 + row_ld) * K + col8;
  const unsigned wbase = (unsigned)(tid & ~63u) * 8;  // elems

  for (int k0 = 0; k0 < K; k0 += 32) {
    __syncthreads();
    gload_lds16(ag + k0, As + wbase);
    gload_lds16(ag + (size_t)64 * K + k0, As + 2048 + wbase);
    gload_lds16(bg + k0, Bs + wbase);
    gload_lds16(bg + (size_t)64 * K + k0, Bs + 2048 + wbase);
    __syncthreads();
    bf16x8 a[4], b[4];
#pragma unroll
    for (int i = 0; i < 4; ++i)
      a[i] = *reinterpret_cast<const bf16x8*>(&As[(mw + i * 16 + l15) * 32 + lg * 8]);
#pragma unroll
    for (int i = 0; i < 4; ++i)
      b[i] = *reinterpret_cast<const bf16x8*>(&Bs[(nw + i * 16 + l15) * 32 + lg * 8]);
#pragma unroll
    for (int i = 0; i < 4; ++i)
#pragma unroll
      for (int j = 0; j < 4; ++j)
        acc[i][j] = __builtin_amdgcn_mfma_f32_16x16x32_bf16(a[i], b[j], acc[i][j], 0, 0, 0);
  }

#pragma unroll
  for (int i = 0; i < 4; ++i)
#pragma unroll
    for (int j = 0; j < 4; ++j) {
      const int col = n0 + nw + j * 16 + l15;
#pragma unroll
      for (int r = 0; r < 4; ++r) {
        const int row = m0 + mw + i * 16 + lg * 4 + r;
        float v = acc[i][j][r];
        if constexpr (MODE == 0) {
          ep.out[(size_t)row * N + col] = (bf16_t)v;
        } else if constexpr (MODE == 1) {
          ep.outf[(size_t)row * N + col] = v + ep.bias[col];
        } else if constexpr (MODE == 2) {
          const int h = col >> 7, d = col & 127;
          const int b = row >> 11, s = row & 2047;
          ep.out[(((size_t)(b * NH + h)) * S_LEN + s) * DF + d] = (bf16_t)v;
        } else if constexpr (MODE == 3) {
          const int h = col >> 7, d = col & 127;
          const int b = row >> 11, s = row & 2047;
          ep.out[(((size_t)(b * NH + h)) * HDIM + d) * S_LEN + s] = (bf16_t)v;
        } else {  // MODE 4: bias + RoPE + scatter at offset 128
          float vb = v + ep.bias[col];
          float other = __shfl_xor(vb, 1, 64);
          const int s = row & 2047, b = row >> 11;
          const int h = col >> 6, dr = col & 63;
          const int fi = dr >> 1;
          const float c = ep.cosb[s * 32 + fi];
          const float sn = ep.sinb[s * 32 + fi];
          const float o = (col & 1) ? (other * sn + vb * c) : (vb * c - other * sn);
          ep.out[(((size_t)(b * NH + h)) * S_LEN + s) * DF + 128 + dr] = (bf16_t)o;
        }
      }
    }
}

// ---------------- flash attention (causal) ----------------
// qf,kf: (B,H,S,192) bf16 ; vT: (B,H,128,S) bf16 ; att: (B,S,H*128) bf16
__global__ __launch_bounds__(256) void attn_fwd(const bf16_t* __restrict__ qf,
                                                const bf16_t* __restrict__ kf,
                                                const bf16_t* __restrict__ vT,
                                                bf16_t* __restrict__ att) {
  const int lane = threadIdx.x & 63, w = threadIdx.x >> 6;
  const int l15 = lane & 15, lg = lane >> 4;
  const int bh = blockIdx.y;
  const int q0 = blockIdx.x * 64 + w * 16;
  __shared__ alignas(16) bf16_t Plds[4][16][40];
  const float scale = 0.07216878364870322f;  // 1/sqrt(192)

  // Q fragments (held for whole loop)
  const bf16_t* qb = qf + ((size_t)bh * S_LEN + q0 + l15) * DF + lg * 8;
  bf16x8 qfr[6];
#pragma unroll
  for (int d = 0; d < 6; ++d) qfr[d] = *reinterpret_cast<const bf16x8*>(qb + d * 32);

  f32x4 o[8] = {};
  float m[4], lsum[4];
#pragma unroll
  for (int r = 0; r < 4; ++r) { m[r] = -1e30f; lsum[r] = 0.0f; }

  const bf16_t* kb0 = kf + (size_t)bh * S_LEN * DF;
  const bf16_t* vb0 = vT + (size_t)bh * HDIM * S_LEN;
  const int njt = (q0 + 15) / 32 + 1;

  for (int jt = 0; jt < njt; ++jt) {
    const int j0 = jt * 32;
    f32x4 sa[2] = {};
#pragma unroll
    for (int hf = 0; hf < 2; ++hf) {
      const bf16_t* kb = kb0 + (size_t)(j0 + hf * 16 + l15) * DF + lg * 8;
#pragma unroll
      for (int d = 0; d < 6; ++d) {
        bf16x8 kfr = *reinterpret_cast<const bf16x8*>(kb + d * 32);
        sa[hf] = __builtin_amdgcn_mfma_f32_16x16x32_bf16(qfr[d], kfr, sa[hf], 0, 0, 0);
      }
    }
    const bool full = (j0 + 31 <= q0);
    float sv[8];
#pragma unroll
    for (int hf = 0; hf < 2; ++hf)
#pragma unroll
      for (int r = 0; r < 4; ++r) {
        float x = sa[hf][r] * scale;
        if (!full) {
          const int j = j0 + hf * 16 + l15;
          const int qi = q0 + lg * 4 + r;
          if (j > qi) x = -1e30f;
        }
        sv[hf * 4 + r] = x;
      }
    float tmax[4];
#pragma unroll
    for (int r = 0; r < 4; ++r) tmax[r] = fmaxf(sv[r], sv[4 + r]);
#pragma unroll
    for (int xm = 1; xm < 16; xm <<= 1)
#pragma unroll
      for (int r = 0; r < 4; ++r) tmax[r] = fmaxf(tmax[r], __shfl_xor(tmax[r], xm, 64));
    float alpha[4];
#pragma unroll
    for (int r = 0; r < 4; ++r) {
      const float mn = fmaxf(m[r], tmax[r]);
      alpha[r] = __expf(m[r] - mn);
      m[r] = mn;
    }
#pragma unroll
    for (int hf = 0; hf < 2; ++hf)
#pragma unroll
      for (int r = 0; r < 4; ++r) sv[hf * 4 + r] = __expf(sv[hf * 4 + r] - m[r]);
    float rs[4];
#pragma unroll
    for (int r = 0; r < 4; ++r) rs[r] = sv[r] + sv[4 + r];
#pragma unroll
    for (int xm = 1; xm < 16; xm <<= 1)
#pragma unroll
      for (int r = 0; r < 4; ++r) rs[r] += __shfl_xor(rs[r], xm, 64);
#pragma unroll
    for (int r = 0; r < 4; ++r) lsum[r] = lsum[r] * alpha[r] + rs[r];
#pragma unroll
    for (int t = 0; t < 8; ++t)
#pragma unroll
      for (int r = 0; r < 4; ++r) o[t][r] *= alpha[r];
    // stage P in LDS (per-wave), re-read in A-fragment layout
#pragma unroll
    for (int hf = 0; hf < 2; ++hf)
#pragma unroll
      for (int r = 0; r < 4; ++r)
        Plds[w][lg * 4 + r][hf * 16 + l15] = (bf16_t)sv[hf * 4 + r];
    asm volatile("s_waitcnt lgkmcnt(0)" ::: "memory");
    bf16x8 pfr = *reinterpret_cast<const bf16x8*>(&Plds[w][l15][lg * 8]);
#pragma unroll
    for (int dt = 0; dt < 8; ++dt) {
      bf16x8 vfr = *reinterpret_cast<const bf16x8*>(
          vb0 + (size_t)(dt * 16 + l15) * S_LEN + j0 + lg * 8);
      o[dt] = __builtin_amdgcn_mfma_f32_16x16x32_bf16(pfr, vfr, o[dt], 0, 0, 0);
    }
  }

  float inv[4];
#pragma unroll
  for (int r = 0; r < 4; ++r) inv[r] = 1.0f / lsum[r];
  const int b = bh >> 4, h = bh & 15;
#pragma unroll
  for (int dt = 0; dt < 8; ++dt)
#pragma unroll
    for (int r = 0; r < 4; ++r) {
      const int s = q0 + lg * 4 + r;
      att[((size_t)b * S_LEN + s) * 2048 + h * 128 + dt * 16 + l15] =
          (bf16_t)(o[dt][r] * inv[r]);
    }
}

// ---------------- host launch ----------------
extern "C" void kernel_launch(void* const* d_in, const int* in_sizes, int n_in,
                              void* d_out, int out_size, void* d_ws, size_t ws_size,
                              hipStream_t stream) {
  const float* x    = (const float*)d_in[0];
  const float* fcos = (const float*)d_in[1];
  const float* fsin = (const float*)d_in[2];
  const float* Wkv  = (const float*)d_in[3];
  const float* Wlq  = (const float*)d_in[4];
  const float* Wq   = (const float*)d_in[5];
  const float* Wk   = (const float*)d_in[6];
  const float* Wv   = (const float*)d_in[7];
  const float* Wqr  = (const float*)d_in[8];
  const float* bqr  = (const float*)d_in[9];
  const float* Wkr  = (const float*)d_in[10];
  const float* bkr  = (const float*)d_in[11];
  const float* Wo   = (const float*)d_in[12];
  const float* bo   = (const float*)d_in[13];
  float* out = (float*)d_out;

  char* ws = (char*)d_ws;
  size_t off = 0;
  auto alloc = [&](size_t bytes) {
    void* p = ws + off;
    off += (bytes + 255) & ~(size_t)255;
    return p;
  };
  bf16_t* xb   = (bf16_t*)alloc((size_t)MROWS * 2048 * 2);
  bf16_t* WlqT = (bf16_t*)alloc((size_t)1536 * 2048 * 2);
  bf16_t* WkvT = (bf16_t*)alloc((size_t)512 * 2048 * 2);
  bf16_t* WkrT = (bf16_t*)alloc((size_t)1024 * 2048 * 2);
  bf16_t* WqT  = (bf16_t*)alloc((size_t)2048 * 1536 * 2);
  bf16_t* WqrT = (bf16_t*)alloc((size_t)1024 * 1536 * 2);
  bf16_t* WkT  = (bf16_t*)alloc((size_t)2048 * 512 * 2);
  bf16_t* WvT  = (bf16_t*)alloc((size_t)2048 * 512 * 2);
  bf16_t* WoT  = (bf16_t*)alloc((size_t)2048 * 2048 * 2);
  bf16_t* cq   = (bf16_t*)alloc((size_t)MROWS * 1536 * 2);
  bf16_t* ckv  = (bf16_t*)alloc((size_t)MROWS * 512 * 2);
  bf16_t* qfb  = (bf16_t*)alloc((size_t)NB * NH * S_LEN * DF * 2);
  bf16_t* kfb  = (bf16_t*)alloc((size_t)NB * NH * S_LEN * DF * 2);
  bf16_t* vTb  = (bf16_t*)alloc((size_t)NB * NH * HDIM * S_LEN * 2);
  bf16_t* attb = (bf16_t*)alloc((size_t)MROWS * 2048 * 2);

  // 1. convert x
  {
    int n4 = (MROWS * 2048) / 4;
    convert_bf16<<<dim3((n4 + 255) / 256), dim3(256), 0, stream>>>(x, xb, n4);
  }
  // 2. transpose weights: (K,N) f32 -> (N,K) bf16
  auto tr = [&](const float* in, bf16_t* o_, int K, int N) {
    transpose_bf16<<<dim3(N / 64, K / 64), dim3(256), 0, stream>>>(in, o_, K, N);
  };
  tr(Wlq, WlqT, 2048, 1536);
  tr(Wkv, WkvT, 2048, 512);
  tr(Wkr, WkrT, 2048, 1024);
  tr(Wq,  WqT,  1536, 2048);
  tr(Wqr, WqrT, 1536, 1024);
  tr(Wk,  WkT,  512,  2048);
  tr(Wv,  WvT,  512,  2048);
  tr(Wo,  WoT,  2048, 2048);

  auto launch_gemm = [&](auto kern, bf16_t* A, bf16_t* Bt, int N, int K, EpiParams ep) {
    kern<<<dim3(N / 128, MROWS / 128), dim3(256), 0, stream>>>(A, Bt, MROWS, N, K, ep);
  };
  EpiParams ep{};

  // 3. cq = xb @ Wlq
  ep = {cq, nullptr, nullptr, nullptr, nullptr};
  launch_gemm(gemm_bt<0>, xb, WlqT, 1536, 2048, ep);
  // 4. ckv = xb @ Wkv
  ep = {ckv, nullptr, nullptr, nullptr, nullptr};
  launch_gemm(gemm_bt<0>, xb, WkvT, 512, 2048, ep);
  // 5. q -> qf[...,0:128]
  ep = {qfb, nullptr, nullptr, nullptr, nullptr};
  launch_gemm(gemm_bt<2>, cq, WqT, 2048, 1536, ep);
  // 6. qr -> rope -> qf[...,128:192]
  ep = {qfb, nullptr, bqr, fcos, fsin};
  launch_gemm(gemm_bt<4>, cq, WqrT, 1024, 1536, ep);
  // 7. k -> kf[...,0:128]
  ep = {kfb, nullptr, nullptr, nullptr, nullptr};
  launch_gemm(gemm_bt<2>, ckv, WkT, 2048, 512, ep);
  // 8. kr -> rope -> kf[...,128:192]
  ep = {kfb, nullptr, bkr, fcos, fsin};
  launch_gemm(gemm_bt<4>, xb, WkrT, 1024, 2048, ep);
  // 9. v -> vT
  ep = {vTb, nullptr, nullptr, nullptr, nullptr};
  launch_gemm(gemm_bt<3>, ckv, WvT, 2048, 512, ep);
  // 10. attention
  attn_fwd<<<dim3(S_LEN / 64, NB * NH), dim3(256), 0, stream>>>(qfb, kfb, vTb, attb);
  // 11. out = att @ Wo + bo  (f32)
  ep = {nullptr, out, bo, nullptr, nullptr};
  launch_gemm(gemm_bt<1>, attb, WoT, 2048, 2048, ep);
}

// Round 2
// 579.243 us; speedup vs baseline: 1.6375x; 1.6375x over previous
//
#include <hip/hip_runtime.h>
#include <hip/hip_bf16.h>
#include <stdint.h>

#define S_LEN 2048
#define NB 2
#define NH 16
#define HDIM 128
#define RDIM 64
#define DF 192          // HDIM + RDIM
#define MROWS 4096      // NB * S_LEN

typedef __bf16 bf16_t;
typedef __attribute__((ext_vector_type(8))) __bf16 bf16x8;
typedef __attribute__((ext_vector_type(4))) __bf16 bf16x4;
typedef __attribute__((ext_vector_type(4))) float f32x4;
typedef __attribute__((ext_vector_type(4))) float float4v;

__device__ __forceinline__ void gload_lds16(const bf16_t* g, bf16_t* l) {
  __builtin_amdgcn_global_load_lds(
      (const __attribute__((address_space(1))) void*)g,
      (__attribute__((address_space(3))) void*)l, 16, 0, 0);
}

// ---------------- convert f32 -> bf16 (contiguous) ----------------
__global__ __launch_bounds__(256) void convert_bf16(const float* __restrict__ in,
                                                    bf16_t* __restrict__ out, int n4) {
  int i = blockIdx.x * 256 + threadIdx.x;
  if (i >= n4) return;
  float4v v = *reinterpret_cast<const float4v*>(&in[(size_t)i * 4]);
  bf16x4 o;
  o[0] = (bf16_t)v[0]; o[1] = (bf16_t)v[1]; o[2] = (bf16_t)v[2]; o[3] = (bf16_t)v[3];
  *reinterpret_cast<bf16x4*>(&out[(size_t)i * 4]) = o;
}

// ---------------- transpose (K,N) f32 -> (N,K) bf16 ----------------
__global__ __launch_bounds__(256) void transpose_bf16(const float* __restrict__ in,
                                                      bf16_t* __restrict__ out,
                                                      int K, int N) {
  __shared__ float t[64][65];
  const int n0 = blockIdx.x * 64, k0 = blockIdx.y * 64;
  const int tx = threadIdx.x & 63, ty = threadIdx.x >> 6;
#pragma unroll
  for (int i = ty; i < 64; i += 4)
    t[i][tx] = in[(size_t)(k0 + i) * N + n0 + tx];
  __syncthreads();
#pragma unroll
  for (int i = ty; i < 64; i += 4)
    out[(size_t)(n0 + i) * K + k0 + tx] = (bf16_t)t[tx][i];
}

// ---------------- GEMM: C(M,N) = A(M,K) * Bt(N,K)^T ----------------
struct EpiParams {
  bf16_t* out;
  float* outf;
  const float* bias;
  const float* cosb;
  const float* sinb;
};

template <int MODE>
__global__ __launch_bounds__(256) void gemm_bt(const bf16_t* __restrict__ A,
                                               const bf16_t* __restrict__ Bt,
                                               int M, int N, int K, EpiParams ep) {
  const int tid = threadIdx.x;
  const int lane = tid & 63, w = tid >> 6;
  const int l15 = lane & 15, lg = lane >> 4;
  const int m0 = blockIdx.y * 128, n0 = blockIdx.x * 128;
  const int mw = (w >> 1) * 64, nw = (w & 1) * 64;
  __shared__ alignas(16) bf16_t As[128 * 32];
  __shared__ alignas(16) bf16_t Bs[128 * 32];

  f32x4 acc[4][4] = {};
  const int row_ld = tid >> 2;            // 0..63
  const int col8 = (tid & 3) * 8;
  const bf16_t* ag = A + (size_t)(m0 + row_ld) * K + col8;
  const bf16_t* bg = Bt + (size_t)(n0 + row_ld) * K + col8;
  const unsigned wbase = (unsigned)(tid & ~63u) * 8;  // elems

  for (int k0 = 0; k0 < K; k0 += 32) {
    __syncthreads();
    gload_lds16(ag + k0, As + wbase);
    gload_lds16(ag + (size_t)64 * K + k0, As + 2048 + wbase);
    gload_lds16(bg + k0, Bs + wbase);
    gload_lds16(bg + (size_t)64 * K + k0, Bs + 2048 + wbase);
    __syncthreads();
    bf16x8 a[4], b[4];
#pragma unroll
    for (int i = 0; i < 4; ++i)
      a[i] = *reinterpret_cast<const bf16x8*>(&As[(mw + i * 16 + l15) * 32 + lg * 8]);
#pragma unroll
    for (int i = 0; i < 4; ++i)
      b[i] = *reinterpret_cast<const bf16x8*>(&Bs[(nw + i * 16 + l15) * 32 + lg * 8]);
#pragma unroll
    for (int i = 0; i < 4; ++i)
#pragma unroll
      for (int j = 0; j < 4; ++j)
        acc[i][j] = __builtin_amdgcn_mfma_f32_16x16x32_bf16(a[i], b[j], acc[i][j], 0, 0, 0);
  }

#pragma unroll
  for (int i = 0; i < 4; ++i)
#pragma unroll
    for (int j = 0; j < 4; ++j) {
      const int col = n0 + nw + j * 16 + l15;
#pragma unroll
      for (int r = 0; r < 4; ++r) {
        const int row = m0 + mw + i * 16 + lg * 4 + r;
        float v = acc[i][j][r];
        if constexpr (MODE == 0) {
          ep.out[(size_t)row * N + col] = (bf16_t)v;
        } else if constexpr (MODE == 1) {
          ep.outf[(size_t)row * N + col] = v + ep.bias[col];
        } else if constexpr (MODE == 2) {
          const int h = col >> 7, d = col & 127;
          const int b = row >> 11, s = row & 2047;
          ep.out[(((size_t)(b * NH + h)) * S_LEN + s) * DF + d] = (bf16_t)v;
        } else if constexpr (MODE == 3) {
          const int h = col >> 7, d = col & 127;
          const int b = row >> 11, s = row & 2047;
          ep.out[(((size_t)(b * NH + h)) * HDIM + d) * S_LEN + s] = (bf16_t)v;
        } else {  // MODE 4: bias + RoPE + scatter at offset 128
          float vb = v + ep.bias[col];
          float other = __shfl_xor(vb, 1, 64);
          const int s = row & 2047, b = row >> 11;
          const int h = col >> 6, dr = col & 63;
          const int fi = dr >> 1;
          const float c = ep.cosb[s * 32 + fi];
          const float sn = ep.sinb[s * 32 + fi];
          const float o = (col & 1) ? (other * sn + vb * c) : (vb * c - other * sn);
          ep.out[(((size_t)(b * NH + h)) * S_LEN + s) * DF + 128 + dr] = (bf16_t)o;
        }
      }
    }
}

// ---------------- flash attention (causal), LDS-staged K/V ----------------
// qf,kf: (B,H,S,192) bf16 ; vT: (B,H,128,S) bf16 ; att: (B,S,H*128) bf16
// Block: 4 waves x 16 q-rows = 64 q rows. KV tile = 64 keys.
// K tile [64][192] and V tile [128][64] staged via global_load_lds with
// XOR swizzle (16B chunk ^= row&7) applied on the GLOBAL source address
// (linear LDS dest) and re-applied on the LDS read side.
__global__ __launch_bounds__(256) void attn_fwd(const bf16_t* __restrict__ qf,
                                                const bf16_t* __restrict__ kf,
                                                const bf16_t* __restrict__ vT,
                                                bf16_t* __restrict__ att) {
  const int tid = threadIdx.x;
  const int lane = tid & 63, w = tid >> 6;
  const int l15 = lane & 15, lg = lane >> 4;
  const int bh = blockIdx.y;
  const int qb0 = ((int)gridDim.x - 1 - (int)blockIdx.x) * 64;  // heavy blocks first
  const int q0 = qb0 + w * 16;
  const float scale = 0.07216878364870322f;  // 1/sqrt(192)

  __shared__ alignas(16) bf16_t Ks[64 * 192];   // 24.5 KB (swizzled)
  __shared__ alignas(16) bf16_t Vs[128 * 64];   // 16 KB (swizzled)
  __shared__ alignas(16) bf16_t Ps[4][16][72];  // per-wave P, +8 pad

  // Q fragments held in registers for the whole loop
  const bf16_t* qb = qf + ((size_t)bh * S_LEN + q0 + l15) * DF + lg * 8;
  bf16x8 qfr[6];
#pragma unroll
  for (int d = 0; d < 6; ++d) qfr[d] = *reinterpret_cast<const bf16x8*>(qb + d * 32);

  f32x4 o[8] = {};
  float m[4], lsum[4];
#pragma unroll
  for (int r = 0; r < 4; ++r) { m[r] = -1e30f; lsum[r] = 0.0f; }

  const bf16_t* kb0 = kf + (size_t)bh * S_LEN * DF;
  const bf16_t* vb0 = vT + (size_t)bh * HDIM * S_LEN;
  const int njt = qb0 / 64 + 1;
  const int wslot = tid & ~63;  // wave-uniform slot base

  for (int jt = 0; jt < njt; ++jt) {
    const int j0 = jt * 64;
    __syncthreads();  // previous tile's reads complete before overwrite
    // ---- stage K tile: 64 rows x 384B = 1536 16B-slots, 6 issues ----
    const bf16_t* kTile = kb0 + (size_t)j0 * DF;
#pragma unroll
    for (int i = 0; i < 6; ++i) {
      const int s = i * 256 + tid;
      const int row = s / 24;
      const int c = s - row * 24;
      const int cs = c ^ (row & 7);
      gload_lds16(kTile + (size_t)row * DF + cs * 8,
                  Ks + (size_t)(i * 256 + wslot) * 8);
    }
    // ---- stage V tile: 128 rows x 128B = 1024 16B-slots, 4 issues ----
    const bf16_t* vTile = vb0 + j0;
#pragma unroll
    for (int i = 0; i < 4; ++i) {
      const int s = i * 256 + tid;
      const int row = s >> 3;
      const int c = s & 7;
      const int cs = c ^ (row & 7);
      gload_lds16(vTile + (size_t)row * S_LEN + cs * 8,
                  Vs + (size_t)(i * 256 + wslot) * 8);
    }
    __syncthreads();  // staged data visible (drains vmcnt)

    // ---- QK^T: 4 j-fragments x 6 K-chunks ----
    f32x4 sa[4] = {};
#pragma unroll
    for (int jf = 0; jf < 4; ++jf) {
      const int krow = jf * 16 + l15;
      const int ksw = krow & 7;
#pragma unroll
      for (int d = 0; d < 6; ++d) {
        const int kc = (4 * d + lg) ^ ksw;
        bf16x8 kfr = *reinterpret_cast<const bf16x8*>(&Ks[krow * 192 + kc * 8]);
        sa[jf] = __builtin_amdgcn_mfma_f32_16x16x32_bf16(qfr[d], kfr, sa[jf], 0, 0, 0);
      }
    }

    const bool full = (j0 + 63 <= q0);
    float sv[16];
#pragma unroll
    for (int jf = 0; jf < 4; ++jf)
#pragma unroll
      for (int r = 0; r < 4; ++r) {
        float x = sa[jf][r] * scale;
        if (!full) {
          const int j = j0 + jf * 16 + l15;
          const int qi = q0 + lg * 4 + r;
          if (j > qi) x = -1e30f;
        }
        sv[jf * 4 + r] = x;
      }

    float tmax[4];
#pragma unroll
    for (int r = 0; r < 4; ++r)
      tmax[r] = fmaxf(fmaxf(sv[r], sv[4 + r]), fmaxf(sv[8 + r], sv[12 + r]));
#pragma unroll
    for (int xm = 1; xm < 16; xm <<= 1)
#pragma unroll
      for (int r = 0; r < 4; ++r) tmax[r] = fmaxf(tmax[r], __shfl_xor(tmax[r], xm, 64));
    float alpha[4];
#pragma unroll
    for (int r = 0; r < 4; ++r) {
      const float mn = fmaxf(m[r], tmax[r]);
      alpha[r] = __expf(m[r] - mn);
      m[r] = mn;
    }
#pragma unroll
    for (int jf = 0; jf < 4; ++jf)
#pragma unroll
      for (int r = 0; r < 4; ++r) sv[jf * 4 + r] = __expf(sv[jf * 4 + r] - m[r]);
    float rs[4];
#pragma unroll
    for (int r = 0; r < 4; ++r)
      rs[r] = (sv[r] + sv[4 + r]) + (sv[8 + r] + sv[12 + r]);
#pragma unroll
    for (int xm = 1; xm < 16; xm <<= 1)
#pragma unroll
      for (int r = 0; r < 4; ++r) rs[r] += __shfl_xor(rs[r], xm, 64);
#pragma unroll
    for (int r = 0; r < 4; ++r) lsum[r] = lsum[r] * alpha[r] + rs[r];
#pragma unroll
    for (int t = 0; t < 8; ++t)
#pragma unroll
      for (int r = 0; r < 4; ++r) o[t][r] *= alpha[r];

    // ---- stage P (per-wave, padded LDS) and read back as A-fragments ----
#pragma unroll
    for (int jf = 0; jf < 4; ++jf)
#pragma unroll
      for (int r = 0; r < 4; ++r)
        Ps[w][lg * 4 + r][jf * 16 + l15] = (bf16_t)sv[jf * 4 + r];
    asm volatile("s_waitcnt lgkmcnt(0)" ::: "memory");
    bf16x8 pfr[2];
#pragma unroll
    for (int jk = 0; jk < 2; ++jk)
      pfr[jk] = *reinterpret_cast<const bf16x8*>(&Ps[w][l15][jk * 32 + lg * 8]);

    // ---- PV: 8 d-tiles x 2 j-chunks ----
#pragma unroll
    for (int dt = 0; dt < 8; ++dt) {
      const int vrow = dt * 16 + l15;
      const int vsw = vrow & 7;
#pragma unroll
      for (int jk = 0; jk < 2; ++jk) {
        const int vc = (jk * 4 + lg) ^ vsw;
        bf16x8 vfr = *reinterpret_cast<const bf16x8*>(&Vs[vrow * 64 + vc * 8]);
        o[dt] = __builtin_amdgcn_mfma_f32_16x16x32_bf16(pfr[jk], vfr, o[dt], 0, 0, 0);
      }
    }
  }

  float inv[4];
#pragma unroll
  for (int r = 0; r < 4; ++r) inv[r] = 1.0f / lsum[r];
  const int b = bh >> 4, h = bh & 15;
#pragma unroll
  for (int dt = 0; dt < 8; ++dt)
#pragma unroll
    for (int r = 0; r < 4; ++r) {
      const int s = q0 + lg * 4 + r;
      att[((size_t)b * S_LEN + s) * 2048 + h * 128 + dt * 16 + l15] =
          (bf16_t)(o[dt][r] * inv[r]);
    }
}

// ---------------- host launch ----------------
extern "C" void kernel_launch(void* const* d_in, const int* in_sizes, int n_in,
                              void* d_out, int out_size, void* d_ws, size_t ws_size,
                              hipStream_t stream) {
  const float* x    = (const float*)d_in[0];
  const float* fcos = (const float*)d_in[1];
  const float* fsin = (const float*)d_in[2];
  const float* Wkv  = (const float*)d_in[3];
  const float* Wlq  = (const float*)d_in[4];
  const float* Wq   = (const float*)d_in[5];
  const float* Wk   = (const float*)d_in[6];
  const float* Wv   = (const float*)d_in[7];
  const float* Wqr  = (const float*)d_in[8];
  const float* bqr  = (const float*)d_in[9];
  const float* Wkr  = (const float*)d_in[10];
  const float* bkr  = (const float*)d_in[11];
  const float* Wo   = (const float*)d_in[12];
  const float* bo   = (const float*)d_in[13];
  float* out = (float*)d_out;

  char* ws = (char*)d_ws;
  size_t off = 0;
  auto alloc = [&](size_t bytes) {
    void* p = ws + off;
    off += (bytes + 255) & ~(size_t)255;
    return p;
  };
  bf16_t* xb   = (bf16_t*)alloc((size_t)MROWS * 2048 * 2);
  bf16_t* WlqT = (bf16_t*)alloc((size_t)1536 * 2048 * 2);
  bf16_t* WkvT = (bf16_t*)alloc((size_t)512 * 2048 * 2);
  bf16_t* WkrT = (bf16_t*)alloc((size_t)1024 * 2048 * 2);
  bf16_t* WqT  = (bf16_t*)alloc((size_t)2048 * 1536 * 2);
  bf16_t* WqrT = (bf16_t*)alloc((size_t)1024 * 1536 * 2);
  bf16_t* WkT  = (bf16_t*)alloc((size_t)2048 * 512 * 2);
  bf16_t* WvT  = (bf16_t*)alloc((size_t)2048 * 512 * 2);
  bf16_t* WoT  = (bf16_t*)alloc((size_t)2048 * 2048 * 2);
  bf16_t* cq   = (bf16_t*)alloc((size_t)MROWS * 1536 * 2);
  bf16_t* ckv  = (bf16_t*)alloc((size_t)MROWS * 512 * 2);
  bf16_t* qfb  = (bf16_t*)alloc((size_t)NB * NH * S_LEN * DF * 2);
  bf16_t* kfb  = (bf16_t*)alloc((size_t)NB * NH * S_LEN * DF * 2);
  bf16_t* vTb  = (bf16_t*)alloc((size_t)NB * NH * HDIM * S_LEN * 2);
  bf16_t* attb = (bf16_t*)alloc((size_t)MROWS * 2048 * 2);

  // 1. convert x
  {
    int n4 = (MROWS * 2048) / 4;
    convert_bf16<<<dim3((n4 + 255) / 256), dim3(256), 0, stream>>>(x, xb, n4);
  }
  // 2. transpose weights: (K,N) f32 -> (N,K) bf16
  auto tr = [&](const float* in, bf16_t* o_, int K, int N) {
    transpose_bf16<<<dim3(N / 64, K / 64), dim3(256), 0, stream>>>(in, o_, K, N);
  };
  tr(Wlq, WlqT, 2048, 1536);
  tr(Wkv, WkvT, 2048, 512);
  tr(Wkr, WkrT, 2048, 1024);
  tr(Wq,  WqT,  1536, 2048);
  tr(Wqr, WqrT, 1536, 1024);
  tr(Wk,  WkT,  512,  2048);
  tr(Wv,  WvT,  512,  2048);
  tr(Wo,  WoT,  2048, 2048);

  auto launch_gemm = [&](auto kern, bf16_t* A, bf16_t* Bt, int N, int K, EpiParams ep) {
    kern<<<dim3(N / 128, MROWS / 128), dim3(256), 0, stream>>>(A, Bt, MROWS, N, K, ep);
  };
  EpiParams ep{};

  // 3. cq = xb @ Wlq
  ep = {cq, nullptr, nullptr, nullptr, nullptr};
  launch_gemm(gemm_bt<0>, xb, WlqT, 1536, 2048, ep);
  // 4. ckv = xb @ Wkv
  ep = {ckv, nullptr, nullptr, nullptr, nullptr};
  launch_gemm(gemm_bt<0>, xb, WkvT, 512, 2048, ep);
  // 5. q -> qf[...,0:128]
  ep = {qfb, nullptr, nullptr, nullptr, nullptr};
  launch_gemm(gemm_bt<2>, cq, WqT, 2048, 1536, ep);
  // 6. qr -> rope -> qf[...,128:192]
  ep = {qfb, nullptr, bqr, fcos, fsin};
  launch_gemm(gemm_bt<4>, cq, WqrT, 1024, 1536, ep);
  // 7. k -> kf[...,0:128]
  ep = {kfb, nullptr, nullptr, nullptr, nullptr};
  launch_gemm(gemm_bt<2>, ckv, WkT, 2048, 512, ep);
  // 8. kr -> rope -> kf[...,128:192]
  ep = {kfb, nullptr, bkr, fcos, fsin};
  launch_gemm(gemm_bt<4>, xb, WkrT, 1024, 2048, ep);
  // 9. v -> vT
  ep = {vTb, nullptr, nullptr, nullptr, nullptr};
  launch_gemm(gemm_bt<3>, ckv, WvT, 2048, 512, ep);
  // 10. attention
  attn_fwd<<<dim3(S_LEN / 64, NB * NH), dim3(256), 0, stream>>>(qfb, kfb, vTb, attb);
  // 11. out = att @ Wo + bo  (f32)
  ep = {nullptr, out, bo, nullptr, nullptr};
  launch_gemm(gemm_bt<1>, attb, WoT, 2048, 2048, ep);
}

// Round 3
// 471.674 us; speedup vs baseline: 2.0109x; 1.2281x over previous
//
#include <hip/hip_runtime.h>
#include <hip/hip_bf16.h>
#include <stdint.h>

#define S_LEN 2048
#define NB 2
#define NH 16
#define HDIM 128
#define RDIM 64
#define DF 192          // HDIM + RDIM
#define MROWS 4096      // NB * S_LEN

typedef __bf16 bf16_t;
typedef __attribute__((ext_vector_type(8))) __bf16 bf16x8;
typedef __attribute__((ext_vector_type(4))) __bf16 bf16x4;
typedef __attribute__((ext_vector_type(4))) float f32x4;
typedef __attribute__((ext_vector_type(4))) float float4v;

__device__ __forceinline__ void gload_lds16(const bf16_t* g, bf16_t* l) {
  __builtin_amdgcn_global_load_lds(
      (const __attribute__((address_space(1))) void*)g,
      (__attribute__((address_space(3))) void*)l, 16, 0, 0);
}

// ---------------- convert f32 -> bf16 (contiguous) ----------------
__global__ __launch_bounds__(256) void convert_bf16(const float* __restrict__ in,
                                                    bf16_t* __restrict__ out, int n4) {
  int i = blockIdx.x * 256 + threadIdx.x;
  if (i >= n4) return;
  float4v v = *reinterpret_cast<const float4v*>(&in[(size_t)i * 4]);
  bf16x4 o;
  o[0] = (bf16_t)v[0]; o[1] = (bf16_t)v[1]; o[2] = (bf16_t)v[2]; o[3] = (bf16_t)v[3];
  *reinterpret_cast<bf16x4*>(&out[(size_t)i * 4]) = o;
}

// ---------------- transpose (K,N) f32 -> (N,K) bf16 ----------------
__global__ __launch_bounds__(256) void transpose_bf16(const float* __restrict__ in,
                                                      bf16_t* __restrict__ out,
                                                      int K, int N) {
  __shared__ float t[64][65];
  const int n0 = blockIdx.x * 64, k0 = blockIdx.y * 64;
  const int tx = threadIdx.x & 63, ty = threadIdx.x >> 6;
#pragma unroll
  for (int i = ty; i < 64; i += 4)
    t[i][tx] = in[(size_t)(k0 + i) * N + n0 + tx];
  __syncthreads();
#pragma unroll
  for (int i = ty; i < 64; i += 4)
    out[(size_t)(n0 + i) * K + k0 + tx] = (bf16_t)t[tx][i];
}

// ---------------- GEMM: C(M,N) = A(M,K) * Bt(N,K)^T ----------------
// MODE 1: f32 out + bias (final projection)
// MODE 5: fused xb@[Wlq|Wkv|Wkr]: col<1536 -> cq ; col<2048 -> ckv ; else kr rope->kf
// MODE 6: fused cq@[Wq|Wqr]:      col<2048 -> qf d<128 ; else qr rope->qf
// MODE 7: fused ckv@[Wk|Wv]:      col<2048 -> kf d<128 ; else v -> vT
struct EpiParams {
  bf16_t* o0;
  bf16_t* o1;
  bf16_t* o2;
  float* outf;
  const float* bias;
  const float* cosb;
  const float* sinb;
};

template <int MODE>
__global__ __launch_bounds__(256) void gemm_bt(const bf16_t* __restrict__ A,
                                               const bf16_t* __restrict__ Bt,
                                               int M, int N, int K, EpiParams ep) {
  const int tid = threadIdx.x;
  const int lane = tid & 63, w = tid >> 6;
  const int l15 = lane & 15, lg = lane >> 4;
  const int m0 = blockIdx.y * 128, n0 = blockIdx.x * 128;
  const int mw = (w >> 1) * 64, nw = (w & 1) * 64;
  __shared__ alignas(16) bf16_t As[128 * 32];
  __shared__ alignas(16) bf16_t Bs[128 * 32];

  f32x4 acc[4][4] = {};
  const int row_ld = tid >> 2;            // 0..63
  const int col8 = (tid & 3) * 8;
  const bf16_t* ag = A + (size_t)(m0 + row_ld) * K + col8;
  const bf16_t* bg = Bt + (size_t)(n0 + row_ld) * K + col8;
  const unsigned wbase = (unsigned)(tid & ~63u) * 8;  // elems

  for (int k0 = 0; k0 < K; k0 += 32) {
    __syncthreads();
    gload_lds16(ag + k0, As + wbase);
    gload_lds16(ag + (size_t)64 * K + k0, As + 2048 + wbase);
    gload_lds16(bg + k0, Bs + wbase);
    gload_lds16(bg + (size_t)64 * K + k0, Bs + 2048 + wbase);
    __syncthreads();
    bf16x8 a[4], b[4];
#pragma unroll
    for (int i = 0; i < 4; ++i)
      a[i] = *reinterpret_cast<const bf16x8*>(&As[(mw + i * 16 + l15) * 32 + lg * 8]);
#pragma unroll
    for (int i = 0; i < 4; ++i)
      b[i] = *reinterpret_cast<const bf16x8*>(&Bs[(nw + i * 16 + l15) * 32 + lg * 8]);
#pragma unroll
    for (int i = 0; i < 4; ++i)
#pragma unroll
      for (int j = 0; j < 4; ++j)
        acc[i][j] = __builtin_amdgcn_mfma_f32_16x16x32_bf16(a[i], b[j], acc[i][j], 0, 0, 0);
  }

#pragma unroll
  for (int i = 0; i < 4; ++i)
#pragma unroll
    for (int j = 0; j < 4; ++j) {
      const int col = n0 + nw + j * 16 + l15;
#pragma unroll
      for (int r = 0; r < 4; ++r) {
        const int row = m0 + mw + i * 16 + lg * 4 + r;
        float v = acc[i][j][r];
        const int b = row >> 11, s = row & 2047;
        if constexpr (MODE == 1) {
          ep.outf[(size_t)row * N + col] = v + ep.bias[col];
        } else if constexpr (MODE == 5) {
          if (col < 1536) {
            ep.o0[(size_t)row * 1536 + col] = (bf16_t)v;
          } else if (col < 2048) {
            ep.o1[(size_t)row * 512 + (col - 1536)] = (bf16_t)v;
          } else {
            const int c2 = col - 2048;
            float vb = v + ep.bias[c2];
            float other = __shfl_xor(vb, 1, 64);
            const int h = c2 >> 6, dr = c2 & 63;
            const int fi = dr >> 1;
            const float c = ep.cosb[s * 32 + fi];
            const float sn = ep.sinb[s * 32 + fi];
            const float o = (c2 & 1) ? (other * sn + vb * c) : (vb * c - other * sn);
            ep.o2[(((size_t)(b * NH + h)) * S_LEN + s) * DF + 128 + dr] = (bf16_t)o;
          }
        } else if constexpr (MODE == 6) {
          if (col < 2048) {
            const int h = col >> 7, d = col & 127;
            ep.o0[(((size_t)(b * NH + h)) * S_LEN + s) * DF + d] = (bf16_t)v;
          } else {
            const int c2 = col - 2048;
            float vb = v + ep.bias[c2];
            float other = __shfl_xor(vb, 1, 64);
            const int h = c2 >> 6, dr = c2 & 63;
            const int fi = dr >> 1;
            const float c = ep.cosb[s * 32 + fi];
            const float sn = ep.sinb[s * 32 + fi];
            const float o = (c2 & 1) ? (other * sn + vb * c) : (vb * c - other * sn);
            ep.o0[(((size_t)(b * NH + h)) * S_LEN + s) * DF + 128 + dr] = (bf16_t)o;
          }
        } else {  // MODE 7
          if (col < 2048) {
            const int h = col >> 7, d = col & 127;
            ep.o0[(((size_t)(b * NH + h)) * S_LEN + s) * DF + d] = (bf16_t)v;
          } else {
            const int c2 = col - 2048;
            const int h = c2 >> 7, d = c2 & 127;
            ep.o1[(((size_t)(b * NH + h)) * HDIM + d) * S_LEN + s] = (bf16_t)v;
          }
        }
      }
    }
}

// ---------------- flash attention (causal), 8-wave blocks ----------------
// qf,kf: (B,H,S,192) bf16 ; vT: (B,H,128,S) bf16 ; att: (B,S,H*128) bf16
// Block: 8 waves x 16 q-rows = 128 q rows. KV tile = 64 keys, shared by all 8 waves.
__global__ __launch_bounds__(512, 4) void attn_fwd(const bf16_t* __restrict__ qf,
                                                   const bf16_t* __restrict__ kf,
                                                   const bf16_t* __restrict__ vT,
                                                   bf16_t* __restrict__ att) {
  const int tid = threadIdx.x;
  const int lane = tid & 63, w = tid >> 6;
  const int l15 = lane & 15, lg = lane >> 4;
  const int bh = blockIdx.y;
  const int qb0 = (15 - (int)blockIdx.x) * 128;  // heavy blocks first
  const int q0 = qb0 + w * 16;
  const float scale = 0.07216878364870322f;  // 1/sqrt(192)

  __shared__ alignas(16) bf16_t Ks[64 * 192];   // 24.5 KB (swizzled)
  __shared__ alignas(16) bf16_t Vs[128 * 64];   // 16 KB (swizzled)
  __shared__ alignas(16) bf16_t Ps[8][16][72];  // per-wave P, 18 KB

  const bf16_t* qb = qf + ((size_t)bh * S_LEN + q0 + l15) * DF + lg * 8;
  bf16x8 qfr[6];
#pragma unroll
  for (int d = 0; d < 6; ++d) qfr[d] = *reinterpret_cast<const bf16x8*>(qb + d * 32);

  f32x4 o[8] = {};
  float m[4], lsum[4];
#pragma unroll
  for (int r = 0; r < 4; ++r) { m[r] = -1e30f; lsum[r] = 0.0f; }

  const bf16_t* kb0 = kf + (size_t)bh * S_LEN * DF;
  const bf16_t* vb0 = vT + (size_t)bh * HDIM * S_LEN;
  const int njt = qb0 / 64 + 2;
  const int wslot = tid & ~63;

  for (int jt = 0; jt < njt; ++jt) {
    const int j0 = jt * 64;
    __syncthreads();  // previous tile's reads complete before overwrite
    // ---- stage K tile: 64 rows x 384B = 1536 16B-slots, 3 issues x 512 ----
    const bf16_t* kTile = kb0 + (size_t)j0 * DF;
#pragma unroll
    for (int i = 0; i < 3; ++i) {
      const int s = i * 512 + tid;
      const int row = s / 24;
      const int c = s - row * 24;
      const int cs = c ^ (row & 7);
      gload_lds16(kTile + (size_t)row * DF + cs * 8,
                  Ks + (size_t)(i * 512 + wslot) * 8);
    }
    // ---- stage V tile: 128 rows x 128B = 1024 16B-slots, 2 issues x 512 ----
    const bf16_t* vTile = vb0 + j0;
#pragma unroll
    for (int i = 0; i < 2; ++i) {
      const int s = i * 512 + tid;
      const int row = s >> 3;
      const int c = s & 7;
      const int cs = c ^ (row & 7);
      gload_lds16(vTile + (size_t)row * S_LEN + cs * 8,
                  Vs + (size_t)(i * 512 + wslot) * 8);
    }
    __syncthreads();  // drains vmcnt -> staged data visible

    if (j0 > q0 + 15) continue;  // fully masked for this wave (barriers at loop top)

    // ---- QK^T: 4 j-fragments x 6 K-chunks ----
    f32x4 sa[4] = {};
#pragma unroll
    for (int jf = 0; jf < 4; ++jf) {
      const int krow = jf * 16 + l15;
      const int ksw = krow & 7;
#pragma unroll
      for (int d = 0; d < 6; ++d) {
        const int kc = (4 * d + lg) ^ ksw;
        bf16x8 kfr = *reinterpret_cast<const bf16x8*>(&Ks[krow * 192 + kc * 8]);
        sa[jf] = __builtin_amdgcn_mfma_f32_16x16x32_bf16(qfr[d], kfr, sa[jf], 0, 0, 0);
      }
    }

    const bool full = (j0 + 63 <= q0);
    float sv[16];
#pragma unroll
    for (int jf = 0; jf < 4; ++jf)
#pragma unroll
      for (int r = 0; r < 4; ++r) {
        float x = sa[jf][r] * scale;
        if (!full) {
          const int j = j0 + jf * 16 + l15;
          const int qi = q0 + lg * 4 + r;
          if (j > qi) x = -1e30f;
        }
        sv[jf * 4 + r] = x;
      }

    float tmax[4];
#pragma unroll
    for (int r = 0; r < 4; ++r)
      tmax[r] = fmaxf(fmaxf(sv[r], sv[4 + r]), fmaxf(sv[8 + r], sv[12 + r]));
#pragma unroll
    for (int xm = 1; xm < 16; xm <<= 1)
#pragma unroll
      for (int r = 0; r < 4; ++r) tmax[r] = fmaxf(tmax[r], __shfl_xor(tmax[r], xm, 64));
    float alpha[4];
#pragma unroll
    for (int r = 0; r < 4; ++r) {
      const float mn = fmaxf(m[r], tmax[r]);
      alpha[r] = __expf(m[r] - mn);
      m[r] = mn;
    }
#pragma unroll
    for (int jf = 0; jf < 4; ++jf)
#pragma unroll
      for (int r = 0; r < 4; ++r) sv[jf * 4 + r] = __expf(sv[jf * 4 + r] - m[r]);
    float rs[4];
#pragma unroll
    for (int r = 0; r < 4; ++r)
      rs[r] = (sv[r] + sv[4 + r]) + (sv[8 + r] + sv[12 + r]);
#pragma unroll
    for (int xm = 1; xm < 16; xm <<= 1)
#pragma unroll
      for (int r = 0; r < 4; ++r) rs[r] += __shfl_xor(rs[r], xm, 64);
#pragma unroll
    for (int r = 0; r < 4; ++r) lsum[r] = lsum[r] * alpha[r] + rs[r];
#pragma unroll
    for (int t = 0; t < 8; ++t)
#pragma unroll
      for (int r = 0; r < 4; ++r) o[t][r] *= alpha[r];

    // ---- stage P (per-wave LDS) and read back as A-fragments ----
#pragma unroll
    for (int jf = 0; jf < 4; ++jf)
#pragma unroll
      for (int r = 0; r < 4; ++r)
        Ps[w][lg * 4 + r][jf * 16 + l15] = (bf16_t)sv[jf * 4 + r];
    asm volatile("s_waitcnt lgkmcnt(0)" ::: "memory");
    __builtin_amdgcn_sched_barrier(0);
    bf16x8 pfr[2];
#pragma unroll
    for (int jk = 0; jk < 2; ++jk)
      pfr[jk] = *reinterpret_cast<const bf16x8*>(&Ps[w][l15][jk * 32 + lg * 8]);

    // ---- PV: 8 d-tiles x 2 j-chunks ----
#pragma unroll
    for (int dt = 0; dt < 8; ++dt) {
      const int vrow = dt * 16 + l15;
      const int vsw = vrow & 7;
#pragma unroll
      for (int jk = 0; jk < 2; ++jk) {
        const int vc = (jk * 4 + lg) ^ vsw;
        bf16x8 vfr = *reinterpret_cast<const bf16x8*>(&Vs[vrow * 64 + vc * 8]);
        o[dt] = __builtin_amdgcn_mfma_f32_16x16x32_bf16(pfr[jk], vfr, o[dt], 0, 0, 0);
      }
    }
  }

  float inv[4];
#pragma unroll
  for (int r = 0; r < 4; ++r) inv[r] = 1.0f / lsum[r];
  const int b = bh >> 4, h = bh & 15;
#pragma unroll
  for (int dt = 0; dt < 8; ++dt)
#pragma unroll
    for (int r = 0; r < 4; ++r) {
      const int s = q0 + lg * 4 + r;
      att[((size_t)b * S_LEN + s) * 2048 + h * 128 + dt * 16 + l15] =
          (bf16_t)(o[dt][r] * inv[r]);
    }
}

// ---------------- host launch ----------------
extern "C" void kernel_launch(void* const* d_in, const int* in_sizes, int n_in,
                              void* d_out, int out_size, void* d_ws, size_t ws_size,
                              hipStream_t stream) {
  const float* x    = (const float*)d_in[0];
  const float* fcos = (const float*)d_in[1];
  const float* fsin = (const float*)d_in[2];
  const float* Wkv  = (const float*)d_in[3];
  const float* Wlq  = (const float*)d_in[4];
  const float* Wq   = (const float*)d_in[5];
  const float* Wk   = (const float*)d_in[6];
  const float* Wv   = (const float*)d_in[7];
  const float* Wqr  = (const float*)d_in[8];
  const float* bqr  = (const float*)d_in[9];
  const float* Wkr  = (const float*)d_in[10];
  const float* bkr  = (const float*)d_in[11];
  const float* Wo   = (const float*)d_in[12];
  const float* bo   = (const float*)d_in[13];
  float* out = (float*)d_out;

  char* ws = (char*)d_ws;
  size_t off = 0;
  auto alloc = [&](size_t bytes) {
    void* p = ws + off;
    off += (bytes + 255) & ~(size_t)255;
    return p;
  };
  bf16_t* xb    = (bf16_t*)alloc((size_t)MROWS * 2048 * 2);
  bf16_t* WcatA = (bf16_t*)alloc((size_t)3072 * 2048 * 2);  // [Wlq|Wkv|Wkr]^T, K=2048
  bf16_t* WcatB = (bf16_t*)alloc((size_t)3072 * 1536 * 2);  // [Wq|Wqr]^T,     K=1536
  bf16_t* WcatC = (bf16_t*)alloc((size_t)4096 * 512 * 2);   // [Wk|Wv]^T,      K=512
  bf16_t* WoT   = (bf16_t*)alloc((size_t)2048 * 2048 * 2);
  bf16_t* cq    = (bf16_t*)alloc((size_t)MROWS * 1536 * 2);
  bf16_t* ckv   = (bf16_t*)alloc((size_t)MROWS * 512 * 2);
  bf16_t* qfb   = (bf16_t*)alloc((size_t)NB * NH * S_LEN * DF * 2);
  bf16_t* kfb   = (bf16_t*)alloc((size_t)NB * NH * S_LEN * DF * 2);
  bf16_t* vTb   = (bf16_t*)alloc((size_t)NB * NH * HDIM * S_LEN * 2);
  bf16_t* attb  = (bf16_t*)alloc((size_t)MROWS * 2048 * 2);

  // 1. convert x
  {
    int n4 = (MROWS * 2048) / 4;
    convert_bf16<<<dim3((n4 + 255) / 256), dim3(256), 0, stream>>>(x, xb, n4);
  }
  // 2. transpose weights into concatenated (N,K) bf16 buffers
  auto tr = [&](const float* in, bf16_t* o_, int K, int N) {
    transpose_bf16<<<dim3(N / 64, K / 64), dim3(256), 0, stream>>>(in, o_, K, N);
  };
  tr(Wlq, WcatA, 2048, 1536);
  tr(Wkv, WcatA + (size_t)1536 * 2048, 2048, 512);
  tr(Wkr, WcatA + (size_t)2048 * 2048, 2048, 1024);
  tr(Wq,  WcatB, 1536, 2048);
  tr(Wqr, WcatB + (size_t)2048 * 1536, 1536, 1024);
  tr(Wk,  WcatC, 512, 2048);
  tr(Wv,  WcatC + (size_t)2048 * 512, 512, 2048);
  tr(Wo,  WoT, 2048, 2048);

  EpiParams ep{};

  // 3. fused: [cq | ckv | kr-rope->kf] = xb @ WcatA^T   (N=3072, K=2048)
  ep = {cq, ckv, kfb, nullptr, bkr, fcos, fsin};
  gemm_bt<5><<<dim3(3072 / 128, MROWS / 128), dim3(256), 0, stream>>>(
      xb, WcatA, MROWS, 3072, 2048, ep);
  // 4. fused: [q->qf | qr-rope->qf] = cq @ WcatB^T      (N=3072, K=1536)
  ep = {qfb, nullptr, nullptr, nullptr, bqr, fcos, fsin};
  gemm_bt<6><<<dim3(3072 / 128, MROWS / 128), dim3(256), 0, stream>>>(
      cq, WcatB, MROWS, 3072, 1536, ep);
  // 5. fused: [k->kf | v->vT] = ckv @ WcatC^T           (N=4096, K=512)
  ep = {kfb, vTb, nullptr, nullptr, nullptr, nullptr, nullptr};
  gemm_bt<7><<<dim3(4096 / 128, MROWS / 128), dim3(256), 0, stream>>>(
      ckv, WcatC, MROWS, 4096, 512, ep);
  // 6. attention
  attn_fwd<<<dim3(S_LEN / 128, NB * NH), dim3(512), 0, stream>>>(qfb, kfb, vTb, attb);
  // 7. out = att @ Wo + bo  (f32)
  ep = {nullptr, nullptr, nullptr, out, bo, nullptr, nullptr};
  gemm_bt<1><<<dim3(2048 / 128, MROWS / 128), dim3(256), 0, stream>>>(
      attb, WoT, MROWS, 2048, 2048, ep);
}